// Round 21
// baseline (71.243 us; speedup 1.0000x reference)
//
#include <hip/hip_runtime.h>
#include <hip/hip_bf16.h>

#define NN 50000
#define NE 800000
#define HALF_N 25024   // multiple of 32 and 4

typedef short short8 __attribute__((ext_vector_type(8)));
typedef float f32x4 __attribute__((ext_vector_type(4)));
typedef unsigned short ushort_t;

// ---- truncation-based bf16 hi/lo split helpers ----
static __device__ __forceinline__ unsigned bits(float f) { return __float_as_uint(f); }
static __device__ __forceinline__ float hi_f(float v) {
  return __uint_as_float(bits(v) & 0xFFFF0000u);
}
static __device__ __forceinline__ ushort_t hi_u(float v) { return (ushort_t)(bits(v) >> 16); }
static __device__ __forceinline__ unsigned pack_hi(float v0, float v1) {
  return (bits(v0) >> 16) | (bits(v1) & 0xFFFF0000u);
}
static __device__ __forceinline__ unsigned pack_lo(float v0, float v1) {
  float l0 = v0 - hi_f(v0), l1 = v1 - hi_f(v1);
  return (bits(l0) >> 16) | (bits(l1) & 0xFFFF0000u);
}

#define MFMA(a, b, c) __builtin_amdgcn_mfma_f32_16x16x32_bf16(a, b, c, 0, 0, 0)

// ---------------- kA: weight-pack hi-only (t < 4096) + CSR offsets (all threads).
__global__ __launch_bounds__(256) void kA_pack_off(
    const float* __restrict__ Wn, const float* __restrict__ Wc,
    const float* __restrict__ Wu, const float* __restrict__ base_w,
    const float* __restrict__ spline_w, const float* __restrict__ scaler,
    const int* __restrict__ seg,
    ushort_t* __restrict__ p1h, ushort_t* __restrict__ p2h,
    ushort_t* __restrict__ p3h, int* __restrict__ off) {
  int t = blockIdx.x * 256 + threadIdx.x;
  if (t < 4096) {
    int l = t & 63, lm = l & 15, lk = l >> 4;
    if (t < 2048) {
      int nt = t >> 8, ks = (t >> 6) & 3;
      int h = nt * 16 + lm;
#pragma unroll
      for (int j = 0; j < 8; ++j) {
        int f = ks * 32 + lk * 8 + j;
        float v = (f < 64) ? Wn[h * 64 + f] : Wc[h * 64 + (f - 64)];
        p1h[t * 8 + j] = hi_u(v);
      }
    }
    if (t < 1024) {
      int nt = t >> 8, ks = (t >> 6) & 3;
      int o = nt * 16 + lm;
#pragma unroll
      for (int j = 0; j < 8; ++j) {
        int hh = ks * 32 + lk * 8 + j;
        p2h[t * 8 + j] = hi_u(Wu[o * 128 + hh]);
      }
    }
    if (t < 3072) {
      int nt = t / 768, ks = (t >> 6) % 12;
      int o = nt * 16 + lm;
#pragma unroll
      for (int j = 0; j < 8; ++j) {
        int k = ks * 32 + lk * 8 + j;
        int i = k / 6, c = k % 6;
        float v = (c == 0) ? base_w[o * 64 + i]
                           : spline_w[(o * 64 + i) * 5 + (c - 1)] * scaler[o * 64 + i];
        p3h[t * 8 + j] = hi_u(v);
      }
    }
  }
  int e = t;
  if (e < NE) {
    int s1 = seg[e];
    if (e == 0) {
      for (int n = 0; n <= s1; ++n) off[n] = 0;
    } else {
      int s0 = seg[e - 1];
      for (int n = s0 + 1; n <= s1; ++n) off[n] = e;
    }
    if (e == NE - 1) {
      for (int n = s1 + 1; n <= NN; ++n) off[n] = NE;
    }
  }
}

// ---------------- kMix: heterogeneous blocks.
// E-role: edge-agg (one wave per node), Sp bf16-hi. BW-bound streaming.
// G-role: 32-node-tile MFMA pipeline (R20 structure). Latency-bound.
// stride==0: all blocks E. stride==1: all blocks G. stride>=2: every stride-th
// block (r==stride-1) is G (1:(stride-1) interleave in dispatch order).
__global__ __launch_bounds__(256, 6) void kMix(
    int eBase, int eEnd, int gBase, int gTiles, int stride,
    const float* __restrict__ x,
    const float* __restrict__ contexts, const float* __restrict__ attn,
    const int* __restrict__ off,
    ushort_t* __restrict__ Sph, float* __restrict__ aprime, float* __restrict__ degw,
    const float* __restrict__ bn, const float* __restrict__ bc,
    const float* __restrict__ bu,
    const ushort_t* __restrict__ p1h, const ushort_t* __restrict__ p2h,
    const ushort_t* __restrict__ p3h,
    const float* __restrict__ gridp, float* __restrict__ out) {
  __shared__ __align__(16) unsigned char arena[24576];
  __shared__ float ap[32], degl[32];

  int b = blockIdx.x;
  int tid = threadIdx.x;
  bool isG;
  int g = 0, eIdx = 0;
  if (stride == 0) { isG = false; eIdx = b; }
  else if (stride == 1) { isG = true; g = b; }
  else {
    int q = b / stride, r = b - q * stride;
    if (r == stride - 1) { isG = true; g = q; }
    else { isG = false; eIdx = q * (stride - 1) + r; }
  }

  if (!isG) {
    // ================= E-role: edge aggregation (k1 body) =================
    int n = eBase + eIdx * 4 + (tid >> 6);
    int lane = tid & 63;
    if (n >= eEnd) return;
    int s = off[n];
    int e_end = off[n + 1];
    int deg_i = e_end - s;

    int sub = lane >> 4;
    int fq = lane & 15;
    const float4* ctx4 = (const float4*)contexts;

    float4 S = make_float4(0.f, 0.f, 0.f, 0.f);
    float A = 0.f;
    if (deg_i > 0) {
      int last = e_end - 1;
      for (int e0 = s; e0 < e_end; e0 += 16) {
        float a[4];
        float4 c[4];
#pragma unroll
        for (int u = 0; u < 4; ++u) {
          int eu = e0 + 4 * u + sub;
          a[u] = (eu < e_end) ? attn[eu] : 0.f;
          c[u] = ctx4[(size_t)min(eu, last) * 16 + fq];
        }
#pragma unroll
        for (int u = 0; u < 4; ++u) {
          S.x += a[u] * c[u].x;
          S.y += a[u] * c[u].y;
          S.z += a[u] * c[u].z;
          S.w += a[u] * c[u].w;
          A += a[u];
        }
      }
    }
#pragma unroll
    for (int m = 16; m <= 32; m <<= 1) {
      S.x += __shfl_xor(S.x, m);
      S.y += __shfl_xor(S.y, m);
      S.z += __shfl_xor(S.z, m);
      S.w += __shfl_xor(S.w, m);
      A += __shfl_xor(A, m);
    }
    float deg = (float)deg_i;
    float inv = 1.f / fmaxf(deg, 1.f);
    if (lane < 16) {
      float ox = S.x * inv, oy = S.y * inv, oz = S.z * inv, ow = S.w * inv;
      uint2 hp;
      hp.x = pack_hi(ox, oy);
      hp.y = pack_hi(oz, ow);
      *(uint2*)&Sph[(size_t)n * 64 + lane * 4] = hp;
    }
    if (lane == 0) { aprime[n] = A * inv; degw[n] = deg; }
    return;
  }

  // ================= G-role: 32-node-tile MFMA pipeline (R20 body) =================
  if (g >= gTiles) return;
  ushort_t* Uh = (ushort_t*)arena;             // [32][128] swizzled (hi: x | Sp)
  ushort_t* Ul = (ushort_t*)(arena + 8192);    // [32][128] (x-lo cols 0..63)
  ushort_t* Th = (ushort_t*)(arena + 16384);   // [32][128] swizzled (T hi)
  ushort_t* Vh = (ushort_t*)arena;             // [32][384] per-uint XOR swizzle
  float*    ot = (float*)arena;                // [32][64] f32 (overlays V head)

  int n0 = gBase + g * 32;
  int w = tid >> 6, l = tid & 63;
  int lm = l & 15, lk = l >> 4;
  const short8* P1h = (const short8*)p1h;
  const short8* P2h = (const short8*)p2h;
  const short8* P3h = (const short8*)p3h;
  int swzA = (lm & 7) << 3;

  // ---- stage: x (hi+lo), Sp (hi only). Swizzled dest.
  {
    const float4* x4 = (const float4*)x;
    const uint4* Sh4 = (const uint4*)Sph;
#pragma unroll
    for (int q = tid; q < 512; q += 256) {
      int row = q >> 4, slot = q & 15;
      int n = n0 + row;
      int idx = (row * 128 + slot * 8) ^ ((row & 7) << 3);
      if (slot < 8) {
        float4 a = make_float4(0.f, 0.f, 0.f, 0.f), bb = a;
        if (n < NN) {
          a = x4[(size_t)n * 16 + slot * 2];
          bb = x4[(size_t)n * 16 + slot * 2 + 1];
        }
        uint4 hp, lp;
        hp.x = pack_hi(a.x, a.y); hp.y = pack_hi(a.z, a.w);
        hp.z = pack_hi(bb.x, bb.y); hp.w = pack_hi(bb.z, bb.w);
        lp.x = pack_lo(a.x, a.y); lp.y = pack_lo(a.z, a.w);
        lp.z = pack_lo(bb.x, bb.y); lp.w = pack_lo(bb.z, bb.w);
        *(uint4*)&Uh[idx] = hp;
        *(uint4*)&Ul[idx] = lp;
      } else {
        uint4 vh = make_uint4(0u, 0u, 0u, 0u);
        if (n < NN) vh = Sh4[(size_t)n * 8 + (slot & 7)];
        *(uint4*)&Uh[idx] = vh;
      }
    }
  }
  if (tid < 32) {
    int n = n0 + tid;
    ap[tid] = (n < NN) ? aprime[n] : 0.f;
    degl[tid] = (n < NN) ? degw[n] : 1.f;
  }
  __syncthreads();  // A

  // ---- GEMM1: wave w -> h-tiles {2w,2w+1}, m-tiles {0,1}. hi all K, x-lo for ks<2.
  f32x4 acc1[2][2];
#pragma unroll
  for (int q = 0; q < 2; ++q)
#pragma unroll
    for (int mt = 0; mt < 2; ++mt) acc1[q][mt] = (f32x4){0.f, 0.f, 0.f, 0.f};
#pragma unroll
  for (int ks = 0; ks < 4; ++ks) {
    short8 bh0 = P1h[((2 * w + 0) * 4 + ks) * 64 + l];
    short8 bh1 = P1h[((2 * w + 1) * 4 + ks) * 64 + l];
#pragma unroll
    for (int mt = 0; mt < 2; ++mt) {
      int ai = ((mt * 16 + lm) * 128 + ks * 32 + lk * 8) ^ swzA;
      short8 ah = *(const short8*)&Uh[ai];
      acc1[0][mt] = MFMA(ah, bh0, acc1[0][mt]);
      acc1[1][mt] = MFMA(ah, bh1, acc1[1][mt]);
      if (ks < 2) {
        short8 al = *(const short8*)&Ul[ai];
        acc1[0][mt] = MFMA(al, bh0, acc1[0][mt]);
        acc1[1][mt] = MFMA(al, bh1, acc1[1][mt]);
      }
    }
  }
#pragma unroll
  for (int q = 0; q < 2; ++q) {
    int h = (2 * w + q) * 16 + lm;
    float bnv = bn[h], bcv = bc[h];
#pragma unroll
    for (int mt = 0; mt < 2; ++mt) {
#pragma unroll
      for (int r = 0; r < 4; ++r) {
        int node = mt * 16 + lk * 4 + r;
        float t = acc1[q][mt][r] + bnv + ap[node] * bcv;
        Th[(node * 128 + h) ^ ((node & 7) << 3)] = hi_u(t);
      }
    }
  }
  __syncthreads();  // B

  // ---- GEMM2 (1-term): wave w -> o-tile w, m-tiles {0,1}.
  f32x4 acc2[2];
  acc2[0] = (f32x4){0.f, 0.f, 0.f, 0.f};
  acc2[1] = (f32x4){0.f, 0.f, 0.f, 0.f};
#pragma unroll
  for (int ks = 0; ks < 4; ++ks) {
    short8 bh = P2h[(w * 4 + ks) * 64 + l];
#pragma unroll
    for (int mt = 0; mt < 2; ++mt) {
      int ai = ((mt * 16 + lm) * 128 + ks * 32 + lk * 8) ^ swzA;
      short8 ah = *(const short8*)&Th[ai];
      acc2[mt] = MFMA(ah, bh, acc2[mt]);
    }
  }
  __syncthreads();  // C

  // ---- spline constants (deferred; uniform)
  float g8[8];
#pragma unroll
  for (int j = 0; j < 8; ++j) g8[j] = gridp[j];
  float r1[7], r2[6];
#pragma unroll
  for (int j = 0; j < 7; ++j) r1[j] = 1.f / (g8[j + 1] - g8[j]);
#pragma unroll
  for (int j = 0; j < 6; ++j) r2[j] = 1.f / (g8[j + 2] - g8[j]);
  float buv = bu[w * 16 + lm];

  // ---- transform -> Vh (hi-only)
#pragma unroll
  for (int mt = 0; mt < 2; ++mt) {
#pragma unroll
    for (int r = 0; r < 4; ++r) {
      float xv = acc2[mt][r] + buv;
      float sil = xv / (1.f + __expf(-xv));
      float b0[7], b1[6], b2[5];
#pragma unroll
      for (int q = 0; q < 7; ++q) b0[q] = (xv >= g8[q] && xv < g8[q + 1]) ? 1.f : 0.f;
#pragma unroll
      for (int q = 0; q < 6; ++q)
        b1[q] = (xv - g8[q]) * r1[q] * b0[q] + (g8[q + 2] - xv) * r1[q + 1] * b0[q + 1];
#pragma unroll
      for (int q = 0; q < 5; ++q)
        b2[q] = (xv - g8[q]) * r2[q] * b1[q] + (g8[q + 3] - xv) * r2[q + 1] * b1[q + 1];
      int ln = mt * 16 + lk * 4 + r;
      int base = ln * 384 + (w * 16 + lm) * 6;
      int sw = (ln & 7) << 3;
      *(unsigned*)&Vh[(base + 0) ^ sw] = pack_hi(sil, b2[0]);
      *(unsigned*)&Vh[(base + 2) ^ sw] = pack_hi(b2[1], b2[2]);
      *(unsigned*)&Vh[(base + 4) ^ sw] = pack_hi(b2[3], b2[4]);
    }
  }
  __syncthreads();  // V ready

  // ---- KAN GEMM (1-term): wave w -> o-tile w, 2 s-tiles.
  f32x4 accK[2];
  accK[0] = (f32x4){0.f, 0.f, 0.f, 0.f};
  accK[1] = (f32x4){0.f, 0.f, 0.f, 0.f};
#pragma unroll
  for (int ks = 0; ks < 12; ++ks) {
    short8 bh = P3h[(w * 12 + ks) * 64 + l];
#pragma unroll
    for (int s = 0; s < 2; ++s) {
      int ri = ((s * 16 + lm) * 384 + ks * 32 + lk * 8) ^ swzA;
      short8 ah = *(const short8*)&Vh[ri];
      accK[s] = MFMA(ah, bh, accK[s]);
    }
  }
  __syncthreads();  // K

  // ---- stage out tile to LDS (f32, XOR swizzle)
#pragma unroll
  for (int s = 0; s < 2; ++s) {
    int o = w * 16 + lm;
#pragma unroll
    for (int r = 0; r < 4; ++r) {
      int ln = s * 16 + lk * 4 + r;
      ot[(ln * 64 + o) ^ ((ln & 7) << 3)] = accK[s][r];
    }
  }
  __syncthreads();  // O

  // ---- coalesced copy-out
  {
    int row2 = tid >> 3, c8 = (tid & 7) * 8;
    int n = n0 + row2;
    if (n < NN) {
      int sw = (row2 & 7) << 3;
      float4 v0 = *(float4*)&ot[((row2 * 64 + c8) ^ sw)];
      float4 v1 = *(float4*)&ot[((row2 * 64 + c8 + 4) ^ sw)];
      if (degl[row2] <= 0.f) {
        v0 = *(const float4*)(x + (size_t)n * 64 + c8);
        v1 = *(const float4*)(x + (size_t)n * 64 + c8 + 4);
      }
      *(float4*)(out + (size_t)n * 64 + c8) = v0;
      *(float4*)(out + (size_t)n * 64 + c8 + 4) = v1;
    }
  }
}

extern "C" void kernel_launch(void* const* d_in, const int* in_sizes, int n_in,
                              void* d_out, int out_size, void* d_ws, size_t ws_size,
                              hipStream_t stream) {
  const float* x        = (const float*)d_in[0];
  const float* contexts = (const float*)d_in[1];
  const float* attn     = (const float*)d_in[2];
  const int*   seg      = (const int*)d_in[3];
  const float* Wn       = (const float*)d_in[4];
  const float* bn       = (const float*)d_in[5];
  const float* Wc       = (const float*)d_in[6];
  const float* bc       = (const float*)d_in[7];
  const float* Wu       = (const float*)d_in[8];
  const float* bu       = (const float*)d_in[9];
  const float* base_w   = (const float*)d_in[10];
  const float* spline_w = (const float*)d_in[11];
  const float* scaler   = (const float*)d_in[12];
  const float* gridp    = (const float*)d_in[13];
  float* out = (float*)d_out;

  ushort_t* us  = (ushort_t*)d_ws;
  ushort_t* Sph = us;                    // 3,200,000
  ushort_t* p1h = Sph + 3200000;         // 16384
  ushort_t* p2h = p1h + 16384;           // 8192
  ushort_t* p3h = p2h + 8192;            // 24576
  float* aprime = (float*)(p3h + 24576); // 50,000
  float* degw   = aprime + 50000;        // 50,000
  int*   off    = (int*)(degw + 50000);  // 50,001

  kA_pack_off<<<3125, 256, 0, stream>>>(Wn, Wc, Wu, base_w, spline_w, scaler, seg,
                                        p1h, p2h, p3h, off);
  // L2: edge-agg half A (nodes [0, 25024)), all-E.  6256 blocks x 4 nodes.
  kMix<<<6256, 256, 0, stream>>>(0, HALF_N, 0, 0, 0,
                                 x, contexts, attn, off, Sph, aprime, degw,
                                 bn, bc, bu, p1h, p2h, p3h, gridp, out);
  // L3: MIXED — E: nodes [25024, 50000) (6256 E-slots, 1:8 interleave);
  //             G: tiles [0, 782) covering nodes [0, 25024). grid = 9*782.
  kMix<<<7038, 256, 0, stream>>>(HALF_N, NN, 0, 782, 9,
                                 x, contexts, attn, off, Sph, aprime, degw,
                                 bn, bc, bu, p1h, p2h, p3h, gridp, out);
  // L4: all-G — tiles covering nodes [25024, 50016) (bounds-checked at NN).
  kMix<<<781, 256, 0, stream>>>(0, 0, HALF_N, 781, 1,
                                x, contexts, attn, off, Sph, aprime, degw,
                                bn, bc, bu, p1h, p2h, p3h, gridp, out);
}